// Round 10
// baseline (776.365 us; speedup 1.0000x reference)
//
#include <hip/hip_runtime.h>

#define NROWS 32768
#define DDIM  512
#define KCENT 8192

// out layout (floats): qout[16777216] loss[16777216] idx[32768] cbv[4194304] counts[8192]
#define O_LOSS 16777216
#define O_IDX  33554432
#define O_CBV  33587200
#define O_CNT  37781504
#define O_PBLK 8388608      // float offset of pblk inside qout region (32 MB in)

typedef float f32x4 __attribute__((ext_vector_type(4)));
typedef _Float16 f16x8 __attribute__((ext_vector_type(8)));

// ---- kernel 0: fp32 -> f16, 8-slot XOR pre-swizzle within each 128B K-chunk ----
// global unit g: row r = g>>6, w = g&63, chunk dk = w>>3, slot u = w&7.
// slot u of (r, dk) holds logical unit u^(r&7): source floats r*512 + (dk*8 + (u^(r&7)))*8
__global__ __launch_bounds__(256) void vq_cvt_swz8(
    const float* __restrict__ src, char* __restrict__ dst)
{
    const int gid = blockIdx.x * 256 + threadIdx.x;   // one 16B f16 unit (8 floats)
    const int r = gid >> 6, w = gid & 63, dk = w >> 3, u = w & 7;
    const float4* p = (const float4*)(src + (size_t)r * DDIM + (dk*8 + (u ^ (r & 7))) * 8);
    float4 a = p[0], b = p[1];
    f16x8 h;
    h[0]=(_Float16)a.x; h[1]=(_Float16)a.y; h[2]=(_Float16)a.z; h[3]=(_Float16)a.w;
    h[4]=(_Float16)b.x; h[5]=(_Float16)b.y; h[6]=(_Float16)b.z; h[7]=(_Float16)b.w;
    *(f16x8*)(dst + (size_t)gid * 16) = h;
}

// ---- kernel 1: centroid squared norms (fp64 accumulate) + counts=1 ----
__global__ __launch_bounds__(256) void vq_cnorm_kernel(
    const float* __restrict__ CB, float* __restrict__ cnorm, float* __restrict__ counts)
{
    const int wid  = threadIdx.x >> 6;
    const int lane = threadIdx.x & 63;
    const int cid  = blockIdx.x * 4 + wid;
    const float4* p = (const float4*)(CB + (size_t)cid * DDIM + lane * 8);
    float4 a = p[0], b = p[1];
    double s = (double)a.x*a.x + (double)a.y*a.y + (double)a.z*a.z + (double)a.w*a.w
             + (double)b.x*b.x + (double)b.y*b.y + (double)b.z*b.z + (double)b.w*b.w;
    #pragma unroll
    for (int off = 32; off > 0; off >>= 1) s += __shfl_down(s, off);
    if (lane == 0) { cnorm[cid] = (float)s; counts[cid] = 1.0f; }
}

__device__ __forceinline__ void t2_merge(float b1, int bi1, float b2, int bi2,
                                         float& a1, int& ai1, float& a2, int& ai2)
{
    if (b1 < a1 || (b1 == a1 && bi1 < ai1)) {
        float o1 = a1; int oi1 = ai1;
        a1 = b1; ai1 = bi1;
        if (b2 < o1 || (b2 == o1 && bi2 < oi1)) { a2 = b2; ai2 = bi2; }
        else                                    { a2 = o1; ai2 = oi1; }
    } else {
        if (b1 < a2 || (b1 == a2 && bi1 < ai2)) { a2 = b1; ai2 = bi1; }
    }
}

__device__ __forceinline__ void gl16(const char* g, const char* l)
{
    __builtin_amdgcn_global_load_lds(
        (const __attribute__((address_space(1))) void*)g,
        (__attribute__((address_space(3))) void*)l, 16, 0, 0);
}

// ---- kernel 2: 128x128 f16 GEMM tile, LDS double-buffered with counted vmcnt ----
// 512 thr, 8 waves (2 row-groups x 4 col-groups); global_load_lds staging
// (linear dest, pre-swizzled global); XOR on ds_read -> conflict-free.
// K-loop uses raw s_barrier + s_waitcnt vmcnt(4): prev step's loads are waited,
// next step's stay in flight -> no vmcnt(0) drain (T4, m218).
__global__ __launch_bounds__(512, 4) void vq_gemm_kernel(
    const char* __restrict__ Xf, const char* __restrict__ Cf,
    const float* __restrict__ cnorm, float4* __restrict__ pblk)
{
    __shared__ __align__(16) char lds[2][32768];   // per buf: A[128][64]f16 | B[128][64]f16

    // XCD mapping: xcd owns col-blocks [xcd*8, xcd*8+8) (1 MB CB slice, L2-resident)
    const int bid = blockIdx.x;
    const int xcd = bid & 7;
    const int idx = bid >> 3;            // 0..2047
    const int cb  = xcd * 8 + (idx & 7); // 0..63
    const int rb  = idx >> 3;            // 0..255

    const int t    = threadIdx.x;
    const int lane = t & 63;
    const int wid  = t >> 6;
    const int wr   = wid >> 2;    // 2 row-groups of 64
    const int wc   = wid & 3;     // 4 col-groups of 32
    const int l15  = lane & 15;
    const int lg   = lane >> 4;

    // staging: 1024 16B units per operand tile; thread covers units t and t+512
    const int r0 = t >> 3,         u0 = t & 7;
    const int r1 = (t + 512) >> 3, u1 = (t + 512) & 7;
    const size_t a0 = (size_t)(rb*128 + r0)*1024 + u0*16;
    const size_t a1 = (size_t)(rb*128 + r1)*1024 + u1*16;
    const size_t b0 = (size_t)(cb*128 + r0)*1024 + u0*16;
    const size_t b1 = (size_t)(cb*128 + r1)*1024 + u1*16;

    f32x4 z4 = {0.f, 0.f, 0.f, 0.f};
    f32x4 a00=z4, a01=z4, a10=z4, a11=z4, a20=z4, a21=z4, a30=z4, a31=z4;

    #define STAGE(step, buf) do {                                   \
        const size_t o_ = (size_t)(step) * 128;                     \
        gl16(Xf + a0 + o_, &lds[buf][t*16]);                        \
        gl16(Xf + a1 + o_, &lds[buf][(t+512)*16]);                  \
        gl16(Cf + b0 + o_, &lds[buf][16384 + t*16]);                \
        gl16(Cf + b1 + o_, &lds[buf][16384 + (t+512)*16]);          \
    } while (0)

    STAGE(0, 0);

    #pragma unroll
    for (int dk = 0; dk < 8; ++dk) {
        if (dk + 1 < 8) STAGE(dk + 1, (dk + 1) & 1);
        // wait ONLY the current buffer's 4 loads (issued one step ago); keep
        // the 4 just-issued in flight. Raw barrier: no compiler vmcnt(0) drain.
        if (dk + 1 < 8) {
            asm volatile("s_waitcnt vmcnt(4)\n\ts_barrier" ::: "memory");
        } else {
            asm volatile("s_waitcnt vmcnt(0)\n\ts_barrier" ::: "memory");
        }
        const char* bb = &lds[dk & 1][0];
        #pragma unroll
        for (int ks = 0; ks < 2; ++ks) {
            const int ku = ks*4 + lg;          // logical 16B unit within the K-chunk
            const int rA0 = wr*64 +  0 + l15, rA1 = wr*64 + 16 + l15;
            const int rA2 = wr*64 + 32 + l15, rA3 = wr*64 + 48 + l15;
            const int rB0 = wc*32 +  0 + l15, rB1 = wc*32 + 16 + l15;
            f16x8 A0 = *(const f16x8*)(bb + rA0*128 + ((ku ^ (rA0 & 7)) * 16));
            f16x8 A1 = *(const f16x8*)(bb + rA1*128 + ((ku ^ (rA1 & 7)) * 16));
            f16x8 A2 = *(const f16x8*)(bb + rA2*128 + ((ku ^ (rA2 & 7)) * 16));
            f16x8 A3 = *(const f16x8*)(bb + rA3*128 + ((ku ^ (rA3 & 7)) * 16));
            f16x8 B0 = *(const f16x8*)(bb + 16384 + rB0*128 + ((ku ^ (rB0 & 7)) * 16));
            f16x8 B1 = *(const f16x8*)(bb + 16384 + rB1*128 + ((ku ^ (rB1 & 7)) * 16));
            a00 = __builtin_amdgcn_mfma_f32_16x16x32_f16(A0, B0, a00, 0, 0, 0);
            a01 = __builtin_amdgcn_mfma_f32_16x16x32_f16(A0, B1, a01, 0, 0, 0);
            a10 = __builtin_amdgcn_mfma_f32_16x16x32_f16(A1, B0, a10, 0, 0, 0);
            a11 = __builtin_amdgcn_mfma_f32_16x16x32_f16(A1, B1, a11, 0, 0, 0);
            a20 = __builtin_amdgcn_mfma_f32_16x16x32_f16(A2, B0, a20, 0, 0, 0);
            a21 = __builtin_amdgcn_mfma_f32_16x16x32_f16(A2, B1, a21, 0, 0, 0);
            a30 = __builtin_amdgcn_mfma_f32_16x16x32_f16(A3, B0, a30, 0, 0, 0);
            a31 = __builtin_amdgcn_mfma_f32_16x16x32_f16(A3, B1, a31, 0, 0, 0);
        }
        // all waves done reading this buffer before it is restaged at dk+2
        asm volatile("s_barrier" ::: "memory");
    }
    #undef STAGE
    __syncthreads();   // full drain before LDS reuse for reduction

    // epilogue: per (m,j) row-slot, top-2 over this block's 128 cols
    const int colbase = cb*128 + wc*32;
    const float cn0 = cnorm[colbase + l15];
    const float cn1 = cnorm[colbase + 16 + l15];
    const int   c0  = colbase + l15;
    const int   c1  = colbase + 16 + l15;
    float4* redq = (float4*)&lds[0][0];    // [128 rows][4 wc]

    #define T2EPI(M, AC0, AC1)                                                   \
        _Pragma("unroll")                                                        \
        for (int j = 0; j < 4; ++j) {                                            \
            float s0 = fmaf(-2.0f, AC0[j], cn0);                                 \
            float s1 = fmaf(-2.0f, AC1[j], cn1);                                 \
            float v1, v2; int i1, i2;                                            \
            if (s0 <= s1) { v1=s0; i1=c0; v2=s1; i2=c1; }                        \
            else          { v1=s1; i1=c1; v2=s0; i2=c0; }                        \
            _Pragma("unroll")                                                    \
            for (int off = 1; off <= 8; off <<= 1) {                             \
                float e1 = __shfl_xor(v1, off), e2 = __shfl_xor(v2, off);        \
                int  f1 = __shfl_xor(i1, off),  f2 = __shfl_xor(i2, off);        \
                t2_merge(e1, f1, e2, f2, v1, i1, v2, i2);                        \
            }                                                                    \
            if (l15 == 0) {                                                      \
                float4 w; w.x = v1; w.y = __int_as_float(i1);                    \
                w.z = v2; w.w = __int_as_float(i2);                              \
                redq[(wr*64 + M*16 + lg*4 + j)*4 + wc] = w;                      \
            }                                                                    \
        }

    T2EPI(0, a00, a01)
    T2EPI(1, a10, a11)
    T2EPI(2, a20, a21)
    T2EPI(3, a30, a31)
    #undef T2EPI

    __syncthreads();
    if (t < 128) {
        float4 e0 = redq[t*4 + 0], e1 = redq[t*4 + 1];
        float4 e2 = redq[t*4 + 2], e3 = redq[t*4 + 3];
        float v1 = e0.x, v2 = e0.z;
        int   i1 = __float_as_int(e0.y), i2 = __float_as_int(e0.w);
        t2_merge(e1.x, __float_as_int(e1.y), e1.z, __float_as_int(e1.w), v1, i1, v2, i2);
        t2_merge(e2.x, __float_as_int(e2.y), e2.z, __float_as_int(e2.w), v1, i1, v2, i2);
        t2_merge(e3.x, __float_as_int(e3.y), e3.z, __float_as_int(e3.w), v1, i1, v2, i2);
        float4 w; w.x = v1; w.y = __int_as_float(i1); w.z = v2; w.w = __int_as_float(i2);
        pblk[((size_t)(rb*128 + t))*64 + cb] = w;
    }
}

// ---- kernel 3: merge 64 col-block top-2's per row -> global top-2 ----
__global__ __launch_bounds__(256) void vq_merge_kernel(
    const float4* __restrict__ pblk, int* __restrict__ pmini2)
{
    const int wid  = threadIdx.x >> 6;
    const int lane = threadIdx.x & 63;
    const int row  = blockIdx.x * 4 + wid;
    float4 e = pblk[(size_t)row*64 + lane];
    float v1 = e.x, v2 = e.z;
    int   i1 = __float_as_int(e.y), i2 = __float_as_int(e.w);
    #pragma unroll
    for (int off = 1; off < 64; off <<= 1) {
        float b1 = __shfl_xor(v1, off), b2 = __shfl_xor(v2, off);
        int  c1 = __shfl_xor(i1, off),  c2 = __shfl_xor(i2, off);
        t2_merge(b1, c1, b2, c2, v1, i1, v2, i2);
    }
    if (lane == 0) { pmini2[row*2 + 0] = i1; pmini2[row*2 + 1] = i2; }
}

// ---- kernel 4: exact fp64 resolve of the 2 candidates + write all outputs ----
__global__ __launch_bounds__(256) void vq_resolve_out(
    const float* __restrict__ X, const float* __restrict__ CB,
    const int* __restrict__ pmini2, float* __restrict__ out)
{
    const int wid  = threadIdx.x >> 6;
    const int lane = threadIdx.x & 63;
    const int row  = blockIdx.x * 4 + wid;
    const int i0 = pmini2[row*2 + 0], i1 = pmini2[row*2 + 1];

    const float4* xp = (const float4*)(X + (size_t)row * DDIM + lane * 8);
    float4 xa = xp[0], xb = xp[1];
    const float4* p0 = (const float4*)(CB + (size_t)i0 * DDIM + lane * 8);
    float4 c0a = p0[0], c0b = p0[1];
    const float4* p1 = (const float4*)(CB + (size_t)i1 * DDIM + lane * 8);
    float4 c1a = p1[0], c1b = p1[1];

    double d0 = 0.0, d1 = 0.0, e;
    e = (double)xa.x - c0a.x; d0 += e*e;  e = (double)xa.y - c0a.y; d0 += e*e;
    e = (double)xa.z - c0a.z; d0 += e*e;  e = (double)xa.w - c0a.w; d0 += e*e;
    e = (double)xb.x - c0b.x; d0 += e*e;  e = (double)xb.y - c0b.y; d0 += e*e;
    e = (double)xb.z - c0b.z; d0 += e*e;  e = (double)xb.w - c0b.w; d0 += e*e;
    e = (double)xa.x - c1a.x; d1 += e*e;  e = (double)xa.y - c1a.y; d1 += e*e;
    e = (double)xa.z - c1a.z; d1 += e*e;  e = (double)xa.w - c1a.w; d1 += e*e;
    e = (double)xb.x - c1b.x; d1 += e*e;  e = (double)xb.y - c1b.y; d1 += e*e;
    e = (double)xb.z - c1b.z; d1 += e*e;  e = (double)xb.w - c1b.w; d1 += e*e;
    #pragma unroll
    for (int off = 1; off < 64; off <<= 1) {
        d0 += __shfl_xor(d0, off);
        d1 += __shfl_xor(d1, off);
    }

    const bool w1 = (d1 < d0) || (d1 == d0 && i1 < i0);
    const int idxw = w1 ? i1 : i0;
    float4 qa, qb;
    qa.x = w1 ? c1a.x : c0a.x;  qa.y = w1 ? c1a.y : c0a.y;
    qa.z = w1 ? c1a.z : c0a.z;  qa.w = w1 ? c1a.w : c0a.w;
    qb.x = w1 ? c1b.x : c0b.x;  qb.y = w1 ? c1b.y : c0b.y;
    qb.z = w1 ? c1b.z : c0b.z;  qb.w = w1 ? c1b.w : c0b.w;

    float4 qoa, loa, qob, lob;
    float d, s;
    d = qa.x - xa.x; qoa.x = xa.x + d; s = d*d; loa.x = s + 0.25f*s;
    d = qa.y - xa.y; qoa.y = xa.y + d; s = d*d; loa.y = s + 0.25f*s;
    d = qa.z - xa.z; qoa.z = xa.z + d; s = d*d; loa.z = s + 0.25f*s;
    d = qa.w - xa.w; qoa.w = xa.w + d; s = d*d; loa.w = s + 0.25f*s;
    d = qb.x - xb.x; qob.x = xb.x + d; s = d*d; lob.x = s + 0.25f*s;
    d = qb.y - xb.y; qob.y = xb.y + d; s = d*d; lob.y = s + 0.25f*s;
    d = qb.z - xb.z; qob.z = xb.z + d; s = d*d; lob.z = s + 0.25f*s;
    d = qb.w - xb.w; qob.w = xb.w + d; s = d*d; lob.w = s + 0.25f*s;

    ((float4*)out)[(size_t)row*128 + lane*2 + 0] = qoa;
    ((float4*)out)[(size_t)row*128 + lane*2 + 1] = qob;
    ((float4*)(out + O_LOSS))[(size_t)row*128 + lane*2 + 0] = loa;
    ((float4*)(out + O_LOSS))[(size_t)row*128 + lane*2 + 1] = lob;
    if (lane == 0) out[O_IDX + row] = (float)idxw;
}

extern "C" void kernel_launch(void* const* d_in, const int* in_sizes, int n_in,
                              void* d_out, int out_size, void* d_ws, size_t ws_size,
                              hipStream_t stream)
{
    const float* X  = (const float*)d_in[0];
    const float* CB = (const float*)d_in[1];
    float* out = (float*)d_out;

    // big scratch parked in out regions (all rewritten by the final kernels)
    char*   XsB  = (char*)out;                    // 32 MB f16 X      (qout front half)
    float4* pblk = (float4*)(out + O_PBLK);       // 32 MB top-2/blk  (qout back half)
    char*   CBsB = (char*)(out + O_LOSS);         //  8 MB f16 CB     (loss region)

    float* cnorm  = (float*)d_ws;                 // 8192 floats
    int*   pmini2 = (int*)(cnorm + KCENT);        // 2*32768 ints

    vq_cvt_swz8<<<(NROWS*64)/256, 256, 0, stream>>>(X, XsB);
    vq_cvt_swz8<<<(KCENT*64)/256, 256, 0, stream>>>(CB, CBsB);
    vq_cnorm_kernel<<<KCENT/4, 256, 0, stream>>>(CB, cnorm, out + O_CNT);
    vq_gemm_kernel<<<(NROWS/128)*(KCENT/128), 512, 0, stream>>>(XsB, CBsB, cnorm, pblk);
    vq_merge_kernel<<<NROWS/4, 256, 0, stream>>>(pblk, pmini2);
    vq_resolve_out<<<NROWS/4, 256, 0, stream>>>(X, CB, pmini2, out);
    hipMemcpyAsync(out + O_CBV, CB, (size_t)KCENT * DDIM * sizeof(float),
                   hipMemcpyDeviceToDevice, stream);
}